// Round 5
// baseline (660.458 us; speedup 1.0000x reference)
//
#include <hip/hip_runtime.h>
#include <hip/hip_bf16.h>
#include <math.h>

// ---------------------------------------------------------------------------
// CART soft-decision-tree fused pipeline, fp32 VALU version (round 5;
// r0-r3 queue timeouts, r4 container failure -> added ws_size hard guard).
//   out[b,o] = (1/T) sum_t relu(sigmoid(xn@P_t - cut_t) @ W1_t + b1_t) @ W2_t * tw_t  + bias
// Folds: BN affine into projection A[f,ts], cut into c2[ts], tw/T into W2eff,
//        b2*tw/T into bias_out.
// Kernels: k_zero -> k_stats -> k_finalize -> k_sparsemax -> k_main -> k_reduce
// ---------------------------------------------------------------------------

#define B_ROWS 65536
#define F_DIM  256
#define T_TREES 32
#define S_DIM  32
#define O_DIM  16
#define NC     1024          // T*S columns of GEMM1
#define BN_EPS 1e-5f

// ws layout (float offsets)
#define WS_SUM    0
#define WS_SUMSQ  256
#define WS_SCALE  512
#define WS_SHIFT  768
#define WS_BIAS   1024        // 16
#define WS_C2     1040        // 1024
#define WS_A      4096        // 256*1024 = 262144
#define WS_PART   266240      // 8 * 65536*16
#define WS_FLOATS_ATOMIC  266240                      // minimum viable footprint
#define WS_FLOATS_PARTIAL (266240 + 8*1048576)

__global__ void k_zero(float* ws) {
    ws[threadIdx.x] = 0.0f;   // zeros WS_SUM + WS_SUMSQ (512 floats), block=512
}

// Column sums: each block handles 128 rows; thread f accumulates feature f.
__global__ void k_stats(const float* __restrict__ x, float* __restrict__ ws) {
    const int f  = threadIdx.x;
    const int r0 = blockIdx.x * 128;
    float s = 0.f, sq = 0.f;
    const float* p = x + (size_t)r0 * F_DIM + f;
#pragma unroll 4
    for (int r = 0; r < 128; ++r) { float v = p[(size_t)r * F_DIM]; s += v; sq += v * v; }
    atomicAdd(&ws[WS_SUM  + f], s);
    atomicAdd(&ws[WS_SUMSQ + f], sq);
}

__global__ void k_finalize(const float* __restrict__ gamma, const float* __restrict__ beta,
                           const float* __restrict__ b2, const float* __restrict__ tw,
                           float* __restrict__ ws) {
    const int f = threadIdx.x;
    const float inv = 1.0f / (float)B_ROWS;
    float mean = ws[WS_SUM + f] * inv;
    float var  = ws[WS_SUMSQ + f] * inv - mean * mean;
    float sc   = gamma[f] / sqrtf(var + BN_EPS);
    ws[WS_SCALE + f] = sc;
    ws[WS_SHIFT + f] = beta[f] - mean * sc;
    if (f < O_DIM) {
        float acc = 0.f;
        for (int t = 0; t < T_TREES; ++t) acc += b2[t * O_DIM + f] * tw[t * O_DIM + f];
        ws[WS_BIAS + f] = acc * (1.0f / (float)T_TREES);
    }
}

// One block per (t,s) column: sort 256 values desc, cumsum, tau, emit
//   A[f, col] = scale[f]*P[f],  c2[col] = sum_f shift[f]*P[f] - cut[col].
__global__ void k_sparsemax(const float* __restrict__ fsm, const float* __restrict__ cut,
                            float* __restrict__ ws) {
    __shared__ float zs[256];
    __shared__ float zo[256];
    __shared__ float csA[256];
    __shared__ float csB[256];
    __shared__ float red[256];
    __shared__ int   redi[256];
    const int tid = threadIdx.x;
    const int col = blockIdx.x;           // t*32 + s
    const int t = col >> 5, s = col & 31;
    const float z = fsm[t * 8192 + tid * 32 + s];
    zo[tid] = z;
    zs[tid] = z;
    // bitonic sort ascending
    for (int size = 2; size <= 256; size <<= 1) {
        for (int stride = size >> 1; stride > 0; stride >>= 1) {
            __syncthreads();
            const int p = tid ^ stride;
            const float a = zs[tid], b = zs[p];
            __syncthreads();
            const bool up    = ((tid & size) == 0);
            const bool lower = ((tid & stride) == 0);
            zs[tid] = (lower == up) ? fminf(a, b) : fmaxf(a, b);
        }
    }
    __syncthreads();
    // descending cumsum via Hillis-Steele
    csA[tid] = zs[255 - tid];
    __syncthreads();
    float* src = csA; float* dst = csB;
    for (int off = 1; off < 256; off <<= 1) {
        float v = src[tid];
        if (tid >= off) v += src[tid - off];
        dst[tid] = v;
        __syncthreads();
        float* tmp = src; src = dst; dst = tmp;
    }
    const float zd = zs[255 - tid];
    const float kk = (float)(tid + 1);
    redi[tid] = (1.0f + kk * zd > src[tid]) ? 1 : 0;
    __syncthreads();
    for (int off = 128; off > 0; off >>= 1) {
        if (tid < off) redi[tid] += redi[tid + off];
        __syncthreads();
    }
    const int ksup = redi[0];
    const float tau = (src[ksup - 1] - 1.0f) / (float)ksup;
    const float P = fmaxf(zo[tid] - tau, 0.0f);
    ws[WS_A + (size_t)tid * NC + col] = ws[WS_SCALE + tid] * P;
    red[tid] = ws[WS_SHIFT + tid] * P;
    __syncthreads();
    for (int off = 128; off > 0; off >>= 1) {
        if (tid < off) red[tid] += red[tid + off];
        __syncthreads();
    }
    if (tid == 0) ws[WS_C2 + col] = red[0] - cut[col];
}

// ---------------------------------------------------------------------------
// Main fused kernel. Block = 256 threads, tile 128 rows x 128 cols (4 trees).
// grid = (512 row-blocks, 8 col-blocks). 8x8 micro-tile per thread.
// LDS union (floats):
//   K-loop:  xT[32][132] @0 (4224), B[32][128] @4224 (4096)
//   trees :  scT[32][132] @0, hT[32][132] @4224, W1[32*33] @8448,
//            W2[32*17] @9504, b1[32] @10048   -> total 10080 floats = 40320 B
// 40320*4 blocks/CU = 161280 <= 163840 (160KB) -> 4 blocks/CU, 4 waves/SIMD.
// ---------------------------------------------------------------------------
template <int ATOMIC>
__global__ __launch_bounds__(256, 4) void k_main(
        const float* __restrict__ x, const float* __restrict__ W1g,
        const float* __restrict__ b1g, const float* __restrict__ W2g,
        const float* __restrict__ twg, float* __restrict__ ws,
        float* __restrict__ out) {
    __shared__ float smem[10080];
    const int tid = threadIdx.x;
    const int tx = tid & 15, ty = tid >> 4;       // 16 x 16 thread grid
    const int r0 = blockIdx.x * 128;
    const int c0 = blockIdx.y * 128;
    const float* A  = ws + WS_A;
    const float* c2 = ws + WS_C2;

    float acc[8][8];
#pragma unroll
    for (int j = 0; j < 8; ++j)
#pragma unroll
        for (int i = 0; i < 8; ++i) acc[j][i] = 0.f;

    const int kq = (tid & 7) * 4;   // k-quad for x staging
    const int rb = tid >> 3;        // row 0..31 for x staging
    const int kb = tid >> 5;        // k 0..7 for A staging
    const int c4 = (tid & 31) * 4;  // col-quad for A staging

    for (int kc = 0; kc < 256; kc += 32) {
        // stage x chunk -> xT[k][132] (transposed, K-major)
#pragma unroll
        for (int m = 0; m < 4; ++m) {
            const int r = rb + 32 * m;
            const float4 v = *(const float4*)&x[(size_t)(r0 + r) * F_DIM + kc + kq];
            smem[(kq + 0) * 132 + r] = v.x;
            smem[(kq + 1) * 132 + r] = v.y;
            smem[(kq + 2) * 132 + r] = v.z;
            smem[(kq + 3) * 132 + r] = v.w;
        }
        // stage A chunk -> B[k][128]
#pragma unroll
        for (int m = 0; m < 4; ++m) {
            const int k = kb + 8 * m;
            const float4 w = *(const float4*)&A[(size_t)(kc + k) * NC + c0 + c4];
            *(float4*)&smem[4224 + k * 128 + c4] = w;
        }
        __syncthreads();
#pragma unroll 8
        for (int k = 0; k < 32; ++k) {
            const float4 xa0 = *(const float4*)&smem[k * 132 + ty * 8];
            const float4 xa1 = *(const float4*)&smem[k * 132 + ty * 8 + 4];
            const float xr[8] = {xa0.x, xa0.y, xa0.z, xa0.w, xa1.x, xa1.y, xa1.z, xa1.w};
            float bb[8];
#pragma unroll
            for (int i = 0; i < 8; ++i) bb[i] = smem[4224 + k * 128 + tx + 16 * i];
#pragma unroll
            for (int j = 0; j < 8; ++j)
#pragma unroll
                for (int i = 0; i < 8; ++i) acc[j][i] = fmaf(xr[j], bb[i], acc[j][i]);
        }
        __syncthreads();
    }

    float c2r[8];
#pragma unroll
    for (int i = 0; i < 8; ++i) c2r[i] = c2[c0 + tx + 16 * i];

    float acc3[8];
#pragma unroll
    for (int j = 0; j < 8; ++j) acc3[j] = 0.f;

    // Must be fully unrolled so acc[j][2*t+q] is statically indexed
    // (runtime index would spill the 64-reg accumulator to scratch, rule #20).
#pragma unroll
    for (int t = 0; t < 4; ++t) {
        const int gt = blockIdx.y * 4 + t;
        __syncthreads();   // prior tree's LDS reads done before overwrite
        // score -> scT[s_local][132]
#pragma unroll
        for (int q = 0; q < 2; ++q) {
            const int i  = 2 * t + q;
            const int sl = tx + 16 * q;
#pragma unroll
            for (int j = 0; j < 8; ++j) {
                const float z = acc[j][i] + c2r[i];
                smem[sl * 132 + ty * 8 + j] = 1.0f / (1.0f + expf(-z));
            }
        }
        // stage W1 [s*33+j]
        {
            const float4 v = *(const float4*)&W1g[(size_t)gt * 1024 + tid * 4];
            const int s = tid >> 3, jj = (tid & 7) * 4;
            smem[8448 + s * 33 + jj + 0] = v.x;
            smem[8448 + s * 33 + jj + 1] = v.y;
            smem[8448 + s * 33 + jj + 2] = v.z;
            smem[8448 + s * 33 + jj + 3] = v.w;
        }
        // stage W2eff = W2 * tw / T  [j*17+o]
        if (tid < 128) {
            const float4 v = *(const float4*)&W2g[(size_t)gt * 512 + tid * 4];
            const int j = tid >> 2, oo = (tid & 3) * 4;
            const float sc = 1.0f / (float)T_TREES;
            smem[9504 + j * 17 + oo + 0] = v.x * twg[gt * 16 + oo + 0] * sc;
            smem[9504 + j * 17 + oo + 1] = v.y * twg[gt * 16 + oo + 1] * sc;
            smem[9504 + j * 17 + oo + 2] = v.z * twg[gt * 16 + oo + 2] * sc;
            smem[9504 + j * 17 + oo + 3] = v.w * twg[gt * 16 + oo + 3] * sc;
        }
        if (tid < 32) smem[10048 + tid] = b1g[gt * 32 + tid];
        __syncthreads();
        // GEMM2: h[r][j2], j2 = 2tx, 2tx+1
        float acc2[8][2];
#pragma unroll
        for (int j = 0; j < 8; ++j) { acc2[j][0] = 0.f; acc2[j][1] = 0.f; }
#pragma unroll 8
        for (int s = 0; s < 32; ++s) {
            const float4 sa0 = *(const float4*)&smem[s * 132 + ty * 8];
            const float4 sa1 = *(const float4*)&smem[s * 132 + ty * 8 + 4];
            const float sr[8] = {sa0.x, sa0.y, sa0.z, sa0.w, sa1.x, sa1.y, sa1.z, sa1.w};
            const float w0 = smem[8448 + s * 33 + 2 * tx];
            const float w1 = smem[8448 + s * 33 + 2 * tx + 1];
#pragma unroll
            for (int j = 0; j < 8; ++j) {
                acc2[j][0] = fmaf(sr[j], w0, acc2[j][0]);
                acc2[j][1] = fmaf(sr[j], w1, acc2[j][1]);
            }
        }
        const float b1a = smem[10048 + 2 * tx];
        const float b1b = smem[10048 + 2 * tx + 1];
        // hT[j2][132] @4224 (disjoint from scT/W1/W2 -> no sync needed before write)
#pragma unroll
        for (int q = 0; q < 2; ++q) {
            const int jc = 2 * tx + q;
#pragma unroll
            for (int j = 0; j < 8; ++j) {
                const float h = acc2[j][q] + (q ? b1b : b1a);
                smem[4224 + jc * 132 + ty * 8 + j] = fmaxf(h, 0.f);
            }
        }
        __syncthreads();
        // GEMM3: o = tx, accumulate across trees
#pragma unroll 8
        for (int jj = 0; jj < 32; ++jj) {
            const float4 ha0 = *(const float4*)&smem[4224 + jj * 132 + ty * 8];
            const float4 ha1 = *(const float4*)&smem[4224 + jj * 132 + ty * 8 + 4];
            const float hr[8] = {ha0.x, ha0.y, ha0.z, ha0.w, ha1.x, ha1.y, ha1.z, ha1.w};
            const float w2 = smem[9504 + jj * 17 + tx];
#pragma unroll
            for (int j = 0; j < 8; ++j) acc3[j] = fmaf(hr[j], w2, acc3[j]);
        }
    }

    if (ATOMIC) {
#pragma unroll
        for (int j = 0; j < 8; ++j)
            atomicAdd(&out[(size_t)(r0 + ty * 8 + j) * 16 + tx], acc3[j]);
    } else {
        float* pp = ws + WS_PART + (size_t)blockIdx.y * (B_ROWS * 16);
#pragma unroll
        for (int j = 0; j < 8; ++j)
            pp[(size_t)(r0 + ty * 8 + j) * 16 + tx] = acc3[j];
    }
}

__global__ void k_reduce(const float* __restrict__ ws, float* __restrict__ out) {
    const int idx = blockIdx.x * 256 + threadIdx.x;
    float s = ws[WS_BIAS + (idx & 15)];
#pragma unroll
    for (int cb = 0; cb < 8; ++cb) s += ws[WS_PART + (size_t)cb * 1048576 + idx];
    out[idx] = s;
}

__global__ void k_init_out(const float* __restrict__ ws, float* __restrict__ out) {
    const int idx = blockIdx.x * 256 + threadIdx.x;
    out[idx] = ws[WS_BIAS + (idx & 15)];
}

extern "C" void kernel_launch(void* const* d_in, const int* in_sizes, int n_in,
                              void* d_out, int out_size, void* d_ws, size_t ws_size,
                              hipStream_t stream) {
    (void)in_sizes; (void)n_in; (void)out_size;
    const float* x     = (const float*)d_in[0];
    const float* gamma = (const float*)d_in[1];
    const float* beta  = (const float*)d_in[2];
    const float* fsm   = (const float*)d_in[3];
    const float* cut   = (const float*)d_in[4];
    const float* W1    = (const float*)d_in[5];
    const float* b1    = (const float*)d_in[6];
    const float* W2    = (const float*)d_in[7];
    const float* b2    = (const float*)d_in[8];
    const float* tw    = (const float*)d_in[9];
    float* out = (float*)d_out;
    float* ws  = (float*)d_ws;

    // R5 guard: if ws can't hold even the atomic-path footprint, launch
    // nothing (clean validation failure instead of OOB writes -> GPU fault
    // -> container death).
    if (ws_size < (size_t)WS_FLOATS_ATOMIC * sizeof(float)) return;

    const bool partial = ws_size >= (size_t)WS_FLOATS_PARTIAL * sizeof(float);

    k_zero<<<1, 512, 0, stream>>>(ws);
    k_stats<<<512, 256, 0, stream>>>(x, ws);
    k_finalize<<<1, 256, 0, stream>>>(gamma, beta, b2, tw, ws);
    k_sparsemax<<<1024, 256, 0, stream>>>(fsm, cut, ws);
    if (partial) {
        k_main<0><<<dim3(512, 8), 256, 0, stream>>>(x, W1, b1, W2, tw, ws, out);
        k_reduce<<<4096, 256, 0, stream>>>(ws, out);
    } else {
        k_init_out<<<4096, 256, 0, stream>>>(ws, out);
        k_main<1><<<dim3(512, 8), 256, 0, stream>>>(x, W1, b1, W2, tw, ws, out);
    }
}